// Round 8
// baseline (362.101 us; speedup 1.0000x reference)
//
#include <hip/hip_runtime.h>
#include <hip/hip_cooperative_groups.h>
#include <hip/hip_bf16.h>
#include <hip/hip_fp16.h>
#include <math.h>

namespace cg = cooperative_groups;

#define HIDDEN   128
#define NCLS     8
#define NSCHEMES 5
#define KNEI     16
#define NFRAG    2048   // 8 t-tiles * 4 k-chunks * 64 lanes

typedef __attribute__((ext_vector_type(8))) short short8;
typedef __attribute__((ext_vector_type(4))) float floatx4;

static __device__ inline unsigned pk2(float x, float y) {
    __hip_bfloat162 v = __float22bfloat162_rn(float2{x, y});
    union { __hip_bfloat162 b; unsigned u; } cv; cv.b = v;
    return cv.u;
}
static __device__ inline unsigned pkh2(float x, float y) {
    __half2 v = __floats2half2_rn(x, y);
    union { __half2 h; unsigned u; } cv; cv.h = v;
    return cv.u;
}

// ============================ fused cooperative kernel ======================
// Phase 0: blocks 0..7 emit W1 as bf16 MFMA B-fragments in fragment order.
// Phase 1: one 64-node tile per block; MFMA layer 1 with coalesced global
//          fragment loads (no frag LDS), fp32 layer 2 + softmax, fp16 probs.
// Phase 2: grid-stride combine (16 lanes/node).
__global__ __launch_bounds__(256, 4) void fused(
    const float* __restrict__ feats, const float* __restrict__ W1,
    const float* __restrict__ b1, const float* __restrict__ W2,
    const float* __restrict__ b2, const int* __restrict__ nei,
    const float* __restrict__ attention, const float* __restrict__ alpha,
    unsigned short* __restrict__ probsh, unsigned short* __restrict__ W1frag,
    float* __restrict__ out, int N)
{
    __shared__ float W2l[HIDDEN * NCLS];   // 4 KB
    __shared__ float b1l[HIDDEN];

    const int tid  = threadIdx.x;
    const int lane = tid & 63;
    const int wv   = tid >> 6;
    const int quad = lane >> 4;
    const int l16  = lane & 15;

    // ---- phase 0: convert W1 -> fragment-ordered bf16 (blocks 0..7)
    if (blockIdx.x < NFRAG / 256) {
        int f = blockIdx.x * 256 + tid;
        int fl = f & 63, c = (f >> 6) & 3, t = f >> 8;
        int q = fl >> 4, m16 = fl & 15;
        int j  = t * 16 + m16;
        int k0 = c * 32 + q * 8;
        union { short8 s; unsigned u[4]; } r;
        #pragma unroll
        for (int p = 0; p < 4; ++p) {
            float a = W1[(size_t)(k0 + 2 * p)     * HIDDEN + j];
            float b = W1[(size_t)(k0 + 2 * p + 1) * HIDDEN + j];
            r.u[p] = pk2(a, b);
        }
        *(short8*)(W1frag + (size_t)f * 8) = r.s;
    }
    // stage W2/b1 to LDS (independent of phase 0 output)
    {
        float4 v = ((const float4*)W2)[tid];
        *(float4*)&W2l[4 * tid] = v;
    }
    if (tid < HIDDEN) b1l[tid] = b1[tid];

    __threadfence();
    cg::this_grid().sync();

    // ---- phase 1: MLP for this block's 64-node tile
    {
        const int nodeBase = blockIdx.x * 64 + wv * 16;
        int myNode = nodeBase + l16;
        if (myNode >= N) myNode = N - 1;

        floatx4 acc[8];
        #pragma unroll
        for (int t = 0; t < 8; ++t) acc[t] = (floatx4){0.f, 0.f, 0.f, 0.f};

        const float* arow = feats + (size_t)myNode * HIDDEN + quad * 8;
        #pragma unroll
        for (int c = 0; c < 4; ++c) {
            float4 a0 = *(const float4*)(arow + c * 32);
            float4 a1 = *(const float4*)(arow + c * 32 + 4);
            union { short8 s; unsigned u[4]; } af;
            af.u[0] = pk2(a0.x, a0.y);
            af.u[1] = pk2(a0.z, a0.w);
            af.u[2] = pk2(a1.x, a1.y);
            af.u[3] = pk2(a1.z, a1.w);
            #pragma unroll
            for (int t = 0; t < 8; ++t) {
                // fragment order -> 64 lanes read 64 consecutive 16 B chunks (1 KiB, L2-hot)
                short8 bf = *(const short8*)(W1frag + (size_t)(((t * 4 + c) * 64) + lane) * 8);
                acc[t] = __builtin_amdgcn_mfma_f32_16x16x32_bf16(af.s, bf, acc[t], 0, 0, 0);
            }
        }

        // layer 2 (fp32): lane holds h[node = quad*4+r][j = t*16+l16]
        float opart[4][NCLS];
        #pragma unroll
        for (int r = 0; r < 4; ++r)
            #pragma unroll
            for (int c = 0; c < NCLS; ++c) opart[r][c] = 0.f;

        #pragma unroll
        for (int t = 0; t < 8; ++t) {
            int j = t * 16 + l16;
            float bj = b1l[j];
            float4 w0 = *(const float4*)&W2l[j * NCLS];
            float4 w1 = *(const float4*)&W2l[j * NCLS + 4];
            #pragma unroll
            for (int r = 0; r < 4; ++r) {
                float h = fmaxf(acc[t][r] + bj, 0.f);
                opart[r][0] = fmaf(h, w0.x, opart[r][0]);
                opart[r][1] = fmaf(h, w0.y, opart[r][1]);
                opart[r][2] = fmaf(h, w0.z, opart[r][2]);
                opart[r][3] = fmaf(h, w0.w, opart[r][3]);
                opart[r][4] = fmaf(h, w1.x, opart[r][4]);
                opart[r][5] = fmaf(h, w1.y, opart[r][5]);
                opart[r][6] = fmaf(h, w1.z, opart[r][6]);
                opart[r][7] = fmaf(h, w1.w, opart[r][7]);
            }
        }

        #pragma unroll
        for (int r = 0; r < 4; ++r)
            #pragma unroll
            for (int c = 0; c < NCLS; ++c) {
                float v = opart[r][c];
                v += __shfl_xor(v, 1, 64);
                v += __shfl_xor(v, 2, 64);
                v += __shfl_xor(v, 4, 64);
                v += __shfl_xor(v, 8, 64);
                opart[r][c] = v;
            }

        if (l16 == 0) {
            float4 b2lo = *(const float4*)b2;
            float4 b2hi = *(const float4*)(b2 + 4);
            float bb[NCLS] = {b2lo.x, b2lo.y, b2lo.z, b2lo.w, b2hi.x, b2hi.y, b2hi.z, b2hi.w};
            #pragma unroll
            for (int r = 0; r < 4; ++r) {
                int n = nodeBase + quad * 4 + r;
                if (n < N) {
                    float o[NCLS];
                    #pragma unroll
                    for (int c = 0; c < NCLS; ++c) o[c] = opart[r][c] + bb[c];
                    float m = o[0];
                    #pragma unroll
                    for (int c = 1; c < NCLS; ++c) m = fmaxf(m, o[c]);
                    float s = 0.f;
                    #pragma unroll
                    for (int c = 0; c < NCLS; ++c) { o[c] = __expf(o[c] - m); s += o[c]; }
                    float inv = 1.f / s;
                    union { short8 s8; unsigned u[4]; } pr;
                    pr.u[0] = pkh2(o[0] * inv, o[1] * inv);
                    pr.u[1] = pkh2(o[2] * inv, o[3] * inv);
                    pr.u[2] = pkh2(o[4] * inv, o[5] * inv);
                    pr.u[3] = pkh2(o[6] * inv, o[7] * inv);
                    *(short8*)(probsh + (size_t)n * NCLS) = pr.s8;
                }
            }
        }
    }

    __threadfence();
    cg::this_grid().sync();

    // ---- phase 2: combine, grid-stride (16 lanes per node)
    const int step = gridDim.x * 256;
    for (int t0 = blockIdx.x * 256 + tid; t0 < N * 16; t0 += step) {
        int n = t0 >> 4;
        int u = t0 & 15;
        int k = u;
        int L = u & 7;

        float aw[NSCHEMES];
        float m = -1e30f;
        #pragma unroll
        for (int s = 0; s < NSCHEMES; ++s) {
            aw[s] = attention[(size_t)n * NSCHEMES + s];
            m = fmaxf(m, aw[s]);
        }
        float ssum = 0.f;
        #pragma unroll
        for (int s = 0; s < NSCHEMES; ++s) { aw[s] = __expf(aw[s] - m); ssum += aw[s]; }

        float g = 1.f / (1.f + __expf(-alpha[n]));
        float scale = (1.f - g) / (ssum * (float)KNEI);
        float wn[NSCHEMES];
        #pragma unroll
        for (int s = 0; s < NSCHEMES; ++s) wn[s] = aw[s] * scale;

        int id[NSCHEMES];
        #pragma unroll
        for (int s = 0; s < NSCHEMES; ++s)
            id[s] = nei[((size_t)s * N + n) * KNEI + k];

        float self;
        {
            union { unsigned short us; __half h; } cv;
            cv.us = probsh[(size_t)n * NCLS + L];
            self = __half2float(cv.h);
        }

        float acc[NCLS];
        #pragma unroll
        for (int c = 0; c < NCLS; ++c) acc[c] = 0.f;
        #pragma unroll
        for (int s = 0; s < NSCHEMES; ++s) {
            union { uint4 v; __half h[8]; } pr;
            pr.v = *(const uint4*)(probsh + (size_t)id[s] * NCLS);
            float w = wn[s];
            #pragma unroll
            for (int c = 0; c < NCLS; ++c)
                acc[c] = fmaf(w, __half2float(pr.h[c]), acc[c]);
        }

        #pragma unroll
        for (int c = 0; c < NCLS; ++c) {
            float v = acc[c];
            v += __shfl_xor(v, 1, 64);
            v += __shfl_xor(v, 2, 64);
            v += __shfl_xor(v, 4, 64);
            v += __shfl_xor(v, 8, 64);
            acc[c] = v;
        }

        if (u < 8) {
            float res = acc[0];
            #pragma unroll
            for (int c = 1; c < NCLS; ++c) res = (u == c) ? acc[c] : res;
            out[(size_t)n * NCLS + u] = fmaf(g, self, res);
        }
    }
}

// ====================== fallback path (R7, three kernels) ===================
__global__ __launch_bounds__(256) void convert_w1(
    const float* __restrict__ W1, unsigned short* __restrict__ W1frag)
{
    int f = blockIdx.x * 256 + threadIdx.x;
    int lane = f & 63, c = (f >> 6) & 3, t = f >> 8;
    int q = lane >> 4, l16 = lane & 15;
    int j  = t * 16 + l16;
    int k0 = c * 32 + q * 8;
    union { short8 s; unsigned u[4]; } r;
    #pragma unroll
    for (int p = 0; p < 4; ++p) {
        float a = W1[(size_t)(k0 + 2 * p)     * HIDDEN + j];
        float b = W1[(size_t)(k0 + 2 * p + 1) * HIDDEN + j];
        r.u[p] = pk2(a, b);
    }
    *(short8*)(W1frag + (size_t)f * 8) = r.s;
}

__global__ __launch_bounds__(256, 4) void mlp_mfma(
    const float* __restrict__ feats, const unsigned short* __restrict__ W1frag,
    const float* __restrict__ b1, const float* __restrict__ W2,
    const float* __restrict__ b2, unsigned short* __restrict__ probsh, int N)
{
    __shared__ float W2l[HIDDEN * NCLS];
    __shared__ float b1l[HIDDEN];

    const int tid  = threadIdx.x;
    const int lane = tid & 63;
    const int wv   = tid >> 6;
    const int quad = lane >> 4;
    const int l16  = lane & 15;
    const int nodeBase = blockIdx.x * 64 + wv * 16;

    {
        float4 v = ((const float4*)W2)[tid];
        *(float4*)&W2l[4 * tid] = v;
    }
    if (tid < HIDDEN) b1l[tid] = b1[tid];
    __syncthreads();

    int myNode = nodeBase + l16;
    if (myNode >= N) myNode = N - 1;

    floatx4 acc[8];
    #pragma unroll
    for (int t = 0; t < 8; ++t) acc[t] = (floatx4){0.f, 0.f, 0.f, 0.f};

    const float* arow = feats + (size_t)myNode * HIDDEN + quad * 8;
    #pragma unroll
    for (int c = 0; c < 4; ++c) {
        float4 a0 = *(const float4*)(arow + c * 32);
        float4 a1 = *(const float4*)(arow + c * 32 + 4);
        union { short8 s; unsigned u[4]; } af;
        af.u[0] = pk2(a0.x, a0.y);
        af.u[1] = pk2(a0.z, a0.w);
        af.u[2] = pk2(a1.x, a1.y);
        af.u[3] = pk2(a1.z, a1.w);
        #pragma unroll
        for (int t = 0; t < 8; ++t) {
            short8 bf = *(const short8*)(W1frag + (size_t)(((t * 4 + c) * 64) + lane) * 8);
            acc[t] = __builtin_amdgcn_mfma_f32_16x16x32_bf16(af.s, bf, acc[t], 0, 0, 0);
        }
    }

    float opart[4][NCLS];
    #pragma unroll
    for (int r = 0; r < 4; ++r)
        #pragma unroll
        for (int c = 0; c < NCLS; ++c) opart[r][c] = 0.f;

    #pragma unroll
    for (int t = 0; t < 8; ++t) {
        int j = t * 16 + l16;
        float bj = b1l[j];
        float4 w0 = *(const float4*)&W2l[j * NCLS];
        float4 w1 = *(const float4*)&W2l[j * NCLS + 4];
        #pragma unroll
        for (int r = 0; r < 4; ++r) {
            float h = fmaxf(acc[t][r] + bj, 0.f);
            opart[r][0] = fmaf(h, w0.x, opart[r][0]);
            opart[r][1] = fmaf(h, w0.y, opart[r][1]);
            opart[r][2] = fmaf(h, w0.z, opart[r][2]);
            opart[r][3] = fmaf(h, w0.w, opart[r][3]);
            opart[r][4] = fmaf(h, w1.x, opart[r][4]);
            opart[r][5] = fmaf(h, w1.y, opart[r][5]);
            opart[r][6] = fmaf(h, w1.z, opart[r][6]);
            opart[r][7] = fmaf(h, w1.w, opart[r][7]);
        }
    }

    #pragma unroll
    for (int r = 0; r < 4; ++r)
        #pragma unroll
        for (int c = 0; c < NCLS; ++c) {
            float v = opart[r][c];
            v += __shfl_xor(v, 1, 64);
            v += __shfl_xor(v, 2, 64);
            v += __shfl_xor(v, 4, 64);
            v += __shfl_xor(v, 8, 64);
            opart[r][c] = v;
        }

    if (l16 == 0) {
        float4 b2lo = *(const float4*)b2;
        float4 b2hi = *(const float4*)(b2 + 4);
        float bb[NCLS] = {b2lo.x, b2lo.y, b2lo.z, b2lo.w, b2hi.x, b2hi.y, b2hi.z, b2hi.w};
        #pragma unroll
        for (int r = 0; r < 4; ++r) {
            int n = nodeBase + quad * 4 + r;
            if (n < N) {
                float o[NCLS];
                #pragma unroll
                for (int c = 0; c < NCLS; ++c) o[c] = opart[r][c] + bb[c];
                float m = o[0];
                #pragma unroll
                for (int c = 1; c < NCLS; ++c) m = fmaxf(m, o[c]);
                float s = 0.f;
                #pragma unroll
                for (int c = 0; c < NCLS; ++c) { o[c] = __expf(o[c] - m); s += o[c]; }
                float inv = 1.f / s;
                union { short8 s8; unsigned u[4]; } pr;
                pr.u[0] = pkh2(o[0] * inv, o[1] * inv);
                pr.u[1] = pkh2(o[2] * inv, o[3] * inv);
                pr.u[2] = pkh2(o[4] * inv, o[5] * inv);
                pr.u[3] = pkh2(o[6] * inv, o[7] * inv);
                *(short8*)(probsh + (size_t)n * NCLS) = pr.s8;
            }
        }
    }
}

__global__ __launch_bounds__(256) void combine(
    const int* __restrict__ nei, const unsigned short* __restrict__ probsh,
    const float* __restrict__ attention, const float* __restrict__ alpha,
    float* __restrict__ out, int N)
{
    int t = blockIdx.x * 256 + threadIdx.x;
    int n = t >> 4;
    int u = t & 15;
    int k = u;
    int L = u & 7;
    if (n >= N) return;

    float aw[NSCHEMES];
    float m = -1e30f;
    #pragma unroll
    for (int s = 0; s < NSCHEMES; ++s) {
        aw[s] = attention[(size_t)n * NSCHEMES + s];
        m = fmaxf(m, aw[s]);
    }
    float ssum = 0.f;
    #pragma unroll
    for (int s = 0; s < NSCHEMES; ++s) { aw[s] = __expf(aw[s] - m); ssum += aw[s]; }

    float g = 1.f / (1.f + __expf(-alpha[n]));
    float scale = (1.f - g) / (ssum * (float)KNEI);
    float wn[NSCHEMES];
    #pragma unroll
    for (int s = 0; s < NSCHEMES; ++s) wn[s] = aw[s] * scale;

    int id[NSCHEMES];
    #pragma unroll
    for (int s = 0; s < NSCHEMES; ++s)
        id[s] = nei[((size_t)s * N + n) * KNEI + k];

    float self;
    {
        union { unsigned short us; __half h; } cv;
        cv.us = probsh[(size_t)n * NCLS + L];
        self = __half2float(cv.h);
    }

    float acc[NCLS];
    #pragma unroll
    for (int c = 0; c < NCLS; ++c) acc[c] = 0.f;
    #pragma unroll
    for (int s = 0; s < NSCHEMES; ++s) {
        union { uint4 v; __half h[8]; } pr;
        pr.v = *(const uint4*)(probsh + (size_t)id[s] * NCLS);
        float w = wn[s];
        #pragma unroll
        for (int c = 0; c < NCLS; ++c)
            acc[c] = fmaf(w, __half2float(pr.h[c]), acc[c]);
    }

    #pragma unroll
    for (int c = 0; c < NCLS; ++c) {
        float v = acc[c];
        v += __shfl_xor(v, 1, 64);
        v += __shfl_xor(v, 2, 64);
        v += __shfl_xor(v, 4, 64);
        v += __shfl_xor(v, 8, 64);
        acc[c] = v;
    }

    if (u < 8) {
        float res = acc[0];
        #pragma unroll
        for (int c = 1; c < NCLS; ++c) res = (u == c) ? acc[c] : res;
        out[(size_t)n * NCLS + u] = fmaf(g, self, res);
    }
}

extern "C" void kernel_launch(void* const* d_in, const int* in_sizes, int n_in,
                              void* d_out, int out_size, void* d_ws, size_t ws_size,
                              hipStream_t stream) {
    const float* feats     = (const float*)d_in[1];
    const float* W1        = (const float*)d_in[2];
    const float* b1        = (const float*)d_in[3];
    const float* W2        = (const float*)d_in[4];
    const float* b2        = (const float*)d_in[5];
    const float* alpha     = (const float*)d_in[6];
    const float* attention = (const float*)d_in[7];
    const int*   sc_nei    = (const int*)d_in[0];
    float* out = (float*)d_out;

    int N = in_sizes[1] / HIDDEN;  // 50000 nodes

    unsigned short* probsh = (unsigned short*)d_ws;                    // N*8 fp16 = 800 KB
    unsigned short* W1frag = (unsigned short*)d_ws + (size_t)N * NCLS; // 32 KB

    int grid = (N + 63) / 64;  // 782 blocks; >= NFRAG/256 = 8; <= coop capacity 1024

    void* args[] = {
        (void*)&feats, (void*)&W1, (void*)&b1, (void*)&W2, (void*)&b2,
        (void*)&sc_nei, (void*)&attention, (void*)&alpha,
        (void*)&probsh, (void*)&W1frag, (void*)&out, (void*)&N
    };
    hipError_t err = hipLaunchCooperativeKernel(
        (const void*)fused, dim3(grid), dim3(256), args, 0, stream);

    if (err != hipSuccess) {
        // deterministic fallback: proven 3-kernel path
        convert_w1<<<NFRAG / 256, 256, 0, stream>>>(W1, W1frag);
        mlp_mfma<<<grid, 256, 0, stream>>>(feats, W1frag, b1, W2, b2, probsh, N);
        combine<<<((N * 16) + 255) / 256, 256, 0, stream>>>(sc_nei, probsh, attention, alpha, out, N);
    }
}

// Round 9
// 123.256 us; speedup vs baseline: 2.9378x; 2.9378x over previous
//
#include <hip/hip_runtime.h>
#include <hip/hip_bf16.h>
#include <hip/hip_fp16.h>
#include <math.h>

#define HIDDEN   128
#define NCLS     8
#define NSCHEMES 5
#define KNEI     16
#define NFRAG    2048   // 8 t-tiles * 4 k-chunks * 64 lanes

typedef __attribute__((ext_vector_type(8))) short short8;
typedef __attribute__((ext_vector_type(4))) float floatx4;

// pack two fp32 -> bf16x2 (RNE) in one dword
static __device__ inline unsigned pk2(float x, float y) {
    __hip_bfloat162 v = __float22bfloat162_rn(float2{x, y});
    union { __hip_bfloat162 b; unsigned u; } cv; cv.b = v;
    return cv.u;
}
// pack two fp32 -> fp16x2 (RNE) in one dword
static __device__ inline unsigned pkh2(float x, float y) {
    __half2 v = __floats2half2_rn(x, y);
    union { __half2 h; unsigned u; } cv; cv.h = v;
    return cv.u;
}

// Emit W1 as bf16 MFMA B-fragments in fragment order:
//   frag f = t*256 + c*64 + lane ; lane = quad*16 + l16
//   frag[f][i] = bf16( W1[c*32 + quad*8 + i][t*16 + l16] ),  i = 0..7  (16 B)
// so the mlp fragment read is a perfectly coalesced 1 KiB per wave-instruction.
__global__ __launch_bounds__(256) void convert_w1(
    const float* __restrict__ W1, unsigned short* __restrict__ W1frag)
{
    int f = blockIdx.x * 256 + threadIdx.x;   // 8 blocks x 256 = 2048
    int lane = f & 63, c = (f >> 6) & 3, t = f >> 8;
    int q = lane >> 4, l16 = lane & 15;
    int j  = t * 16 + l16;
    int k0 = c * 32 + q * 8;
    union { short8 s; unsigned u[4]; } r;
    #pragma unroll
    for (int p = 0; p < 4; ++p) {
        float a = W1[(size_t)(k0 + 2 * p)     * HIDDEN + j];
        float b = W1[(size_t)(k0 + 2 * p + 1) * HIDDEN + j];
        r.u[p] = pk2(a, b);
    }
    *(short8*)(W1frag + (size_t)f * 8) = r.s;
}

// One wave = 16 nodes, block = 64 nodes. Layer 1: MFMA 16x16x32_bf16, A from
// fp32 feats (cvt_pk on the fly), B fragments read coalesced from fragment-
// ordered W1frag (L2-hot, no LDS round-trip). Layer 2 + softmax in fp32 from
// the C-layout accumulators (row = quad*4+reg, col = l16); probs stored as
// fp16 rows (16 B) for single-gather combine.
__global__ __launch_bounds__(256, 4) void mlp_mfma(
    const float* __restrict__ feats, const unsigned short* __restrict__ W1frag,
    const float* __restrict__ b1, const float* __restrict__ W2,
    const float* __restrict__ b2, unsigned short* __restrict__ probsh, int N)
{
    __shared__ float W2l[HIDDEN * NCLS];   // 4 KB
    __shared__ float b1l[HIDDEN];

    const int tid  = threadIdx.x;
    const int lane = tid & 63;
    const int wv   = tid >> 6;
    const int quad = lane >> 4;
    const int l16  = lane & 15;
    const int nodeBase = blockIdx.x * 64 + wv * 16;

    {
        float4 v = ((const float4*)W2)[tid];   // 256 float4 == whole W2
        *(float4*)&W2l[4 * tid] = v;
    }
    if (tid < HIDDEN) b1l[tid] = b1[tid];
    __syncthreads();

    int myNode = nodeBase + l16;
    if (myNode >= N) myNode = N - 1;

    floatx4 acc[8];
    #pragma unroll
    for (int t = 0; t < 8; ++t) acc[t] = (floatx4){0.f, 0.f, 0.f, 0.f};

    const float* arow = feats + (size_t)myNode * HIDDEN + quad * 8;
    #pragma unroll
    for (int c = 0; c < 4; ++c) {              // K-chunks of 32
        float4 a0 = *(const float4*)(arow + c * 32);
        float4 a1 = *(const float4*)(arow + c * 32 + 4);
        union { short8 s; unsigned u[4]; } af;
        af.u[0] = pk2(a0.x, a0.y);
        af.u[1] = pk2(a0.z, a0.w);
        af.u[2] = pk2(a1.x, a1.y);
        af.u[3] = pk2(a1.z, a1.w);
        #pragma unroll
        for (int t = 0; t < 8; ++t) {          // j-tiles of 16
            short8 bf = *(const short8*)(W1frag + (size_t)(((t * 4 + c) * 64) + lane) * 8);
            acc[t] = __builtin_amdgcn_mfma_f32_16x16x32_bf16(af.s, bf, acc[t], 0, 0, 0);
        }
    }

    // ---- layer 2 (fp32): lane holds h[node = quad*4+r][j = t*16+l16]
    float opart[4][NCLS];
    #pragma unroll
    for (int r = 0; r < 4; ++r)
        #pragma unroll
        for (int c = 0; c < NCLS; ++c) opart[r][c] = 0.f;

    #pragma unroll
    for (int t = 0; t < 8; ++t) {
        int j = t * 16 + l16;
        float bj = b1l[j];
        float4 w0 = *(const float4*)&W2l[j * NCLS];
        float4 w1 = *(const float4*)&W2l[j * NCLS + 4];
        #pragma unroll
        for (int r = 0; r < 4; ++r) {
            float h = fmaxf(acc[t][r] + bj, 0.f);
            opart[r][0] = fmaf(h, w0.x, opart[r][0]);
            opart[r][1] = fmaf(h, w0.y, opart[r][1]);
            opart[r][2] = fmaf(h, w0.z, opart[r][2]);
            opart[r][3] = fmaf(h, w0.w, opart[r][3]);
            opart[r][4] = fmaf(h, w1.x, opart[r][4]);
            opart[r][5] = fmaf(h, w1.y, opart[r][5]);
            opart[r][6] = fmaf(h, w1.z, opart[r][6]);
            opart[r][7] = fmaf(h, w1.w, opart[r][7]);
        }
    }

    // reduce over the 16 j-lanes (butterfly stays in the 16-lane group)
    #pragma unroll
    for (int r = 0; r < 4; ++r)
        #pragma unroll
        for (int c = 0; c < NCLS; ++c) {
            float v = opart[r][c];
            v += __shfl_xor(v, 1, 64);
            v += __shfl_xor(v, 2, 64);
            v += __shfl_xor(v, 4, 64);
            v += __shfl_xor(v, 8, 64);
            opart[r][c] = v;
        }

    if (l16 == 0) {   // one lane per quad finalizes its 4 nodes
        float4 b2lo = *(const float4*)b2;
        float4 b2hi = *(const float4*)(b2 + 4);
        float bb[NCLS] = {b2lo.x, b2lo.y, b2lo.z, b2lo.w, b2hi.x, b2hi.y, b2hi.z, b2hi.w};
        #pragma unroll
        for (int r = 0; r < 4; ++r) {
            int n = nodeBase + quad * 4 + r;
            if (n < N) {
                float o[NCLS];
                #pragma unroll
                for (int c = 0; c < NCLS; ++c) o[c] = opart[r][c] + bb[c];
                float m = o[0];
                #pragma unroll
                for (int c = 1; c < NCLS; ++c) m = fmaxf(m, o[c]);
                float s = 0.f;
                #pragma unroll
                for (int c = 0; c < NCLS; ++c) { o[c] = __expf(o[c] - m); s += o[c]; }
                float inv = 1.f / s;
                union { short8 s8; unsigned u[4]; } pr;
                pr.u[0] = pkh2(o[0] * inv, o[1] * inv);
                pr.u[1] = pkh2(o[2] * inv, o[3] * inv);
                pr.u[2] = pkh2(o[4] * inv, o[5] * inv);
                pr.u[3] = pkh2(o[6] * inv, o[7] * inv);
                *(short8*)(probsh + (size_t)n * NCLS) = pr.s8;
            }
        }
    }
}

// 16 lanes per node: u = (kh<<3)|L. Thread handles neighbor k = u for all 5
// schemes: phase A = 5 independent coalesced idx loads, phase B = 5
// independent 16 B fp16-row gathers (2 exposed latencies). 4-step shfl_xor
// butterfly over the 16-lane group; lanes u<8 emit class u.
__global__ __launch_bounds__(256) void combine(
    const int* __restrict__ nei, const unsigned short* __restrict__ probsh,
    const float* __restrict__ attention, const float* __restrict__ alpha,
    float* __restrict__ out, int N)
{
    int t = blockIdx.x * 256 + threadIdx.x;
    int n = t >> 4;
    int u = t & 15;
    int k = u;
    int L = u & 7;
    if (n >= N) return;

    float aw[NSCHEMES];
    float m = -1e30f;
    #pragma unroll
    for (int s = 0; s < NSCHEMES; ++s) {
        aw[s] = attention[(size_t)n * NSCHEMES + s];
        m = fmaxf(m, aw[s]);
    }
    float ssum = 0.f;
    #pragma unroll
    for (int s = 0; s < NSCHEMES; ++s) { aw[s] = __expf(aw[s] - m); ssum += aw[s]; }

    float g = 1.f / (1.f + __expf(-alpha[n]));
    float scale = (1.f - g) / (ssum * (float)KNEI);
    float wn[NSCHEMES];
    #pragma unroll
    for (int s = 0; s < NSCHEMES; ++s) wn[s] = aw[s] * scale;

    int id[NSCHEMES];
    #pragma unroll
    for (int s = 0; s < NSCHEMES; ++s)
        id[s] = nei[((size_t)s * N + n) * KNEI + k];

    float self;
    {
        union { unsigned short us; __half h; } cv;
        cv.us = probsh[(size_t)n * NCLS + L];
        self = __half2float(cv.h);
    }

    float acc[NCLS];
    #pragma unroll
    for (int c = 0; c < NCLS; ++c) acc[c] = 0.f;
    #pragma unroll
    for (int s = 0; s < NSCHEMES; ++s) {
        union { uint4 v; __half h[8]; } pr;
        pr.v = *(const uint4*)(probsh + (size_t)id[s] * NCLS);
        float w = wn[s];
        #pragma unroll
        for (int c = 0; c < NCLS; ++c)
            acc[c] = fmaf(w, __half2float(pr.h[c]), acc[c]);
    }

    #pragma unroll
    for (int c = 0; c < NCLS; ++c) {
        float v = acc[c];
        v += __shfl_xor(v, 1, 64);
        v += __shfl_xor(v, 2, 64);
        v += __shfl_xor(v, 4, 64);
        v += __shfl_xor(v, 8, 64);
        acc[c] = v;
    }

    if (u < 8) {
        float res = acc[0];
        #pragma unroll
        for (int c = 1; c < NCLS; ++c) res = (u == c) ? acc[c] : res;
        out[(size_t)n * NCLS + u] = fmaf(g, self, res);
    }
}

extern "C" void kernel_launch(void* const* d_in, const int* in_sizes, int n_in,
                              void* d_out, int out_size, void* d_ws, size_t ws_size,
                              hipStream_t stream) {
    const int*   sc_nei    = (const int*)d_in[0];
    const float* feats     = (const float*)d_in[1];
    const float* W1        = (const float*)d_in[2];
    const float* b1        = (const float*)d_in[3];
    const float* W2        = (const float*)d_in[4];
    const float* b2        = (const float*)d_in[5];
    const float* alpha     = (const float*)d_in[6];
    const float* attention = (const float*)d_in[7];
    float* out = (float*)d_out;

    int N = in_sizes[1] / HIDDEN;  // 50000 nodes

    unsigned short* probsh = (unsigned short*)d_ws;                    // N*8 fp16 = 800 KB
    unsigned short* W1frag = (unsigned short*)d_ws + (size_t)N * NCLS; // 32 KB, 16 B aligned

    convert_w1<<<NFRAG / 256, 256, 0, stream>>>(W1, W1frag);
    mlp_mfma<<<(N + 63) / 64, 256, 0, stream>>>(feats, W1frag, b1, W2, b2, probsh, N);
    combine<<<((N * 16) + 255) / 256, 256, 0, stream>>>(sc_nei, probsh, attention, alpha, out, N);
}